// Round 1
// baseline (369.190 us; speedup 1.0000x reference)
//
#include <hip/hip_runtime.h>

// out[1,8192] = x[1,8192] @ W[8192,8192] + b[8192]   (all fp32)
// Memory-bound: stream W (256 MiB) once. Roofline floor for the matvec
// stage is ~43 us at 6.3 TB/s achievable HBM BW.
//
// Structure:
//   stage 1: 2048 blocks (8 col-chunks x 256 k-chunks), each thread owns one
//            float4 column slice of a 32-row K-chunk; writes float4 partials
//            to d_ws (8 MB, no atomics, no contention).
//   stage 2: 8 blocks; each thread sums 256 partials for its float4 column,
//            adds bias, stores. (~16 MB extra traffic total, ~3-5 us.)
//
// vs previous version (512 blocks + 64-way atomicAdd per address):
//   - 4x block parallelism: 2 -> 8 blocks/CU (was 2 waves/SIMD -> latency-bound)
//   - no atomic RMW serialization on out
//   - init kernel eliminated (bias fused into stage 2)

#define IN_LEN    8192
#define OUT_LEN   8192
#define THREADS   256
#define K_CHUNK   32                       // rows per stage-1 block
#define N_KCHUNK  (IN_LEN / K_CHUNK)       // 256
#define COL4      (OUT_LEN / 4)            // 2048 float4 columns
#define N_CBLK    (COL4 / THREADS)         // 8 column blocks

// Stage 1: part[kc][0:8192] = sum_{i in chunk kc} x[i] * W[i][:]
__global__ __launch_bounds__(THREADS, 4)
void matvec_partial_kernel(const float* __restrict__ x,
                           const float* __restrict__ W,
                           float* __restrict__ part) {
    const int col4  = blockIdx.x * THREADS + threadIdx.x;   // float4 column
    const int kc    = blockIdx.y;
    const int kbase = kc * K_CHUNK;

    const float4* __restrict__ W4 = (const float4*)W + (size_t)kbase * COL4 + col4;
    float4 acc = make_float4(0.f, 0.f, 0.f, 0.f);

#pragma unroll 8
    for (int i = 0; i < K_CHUNK; ++i) {
        const float  xs = x[kbase + i];          // wave-uniform -> s_load
        const float4 w  = W4[(size_t)i * COL4];  // 1 KB/wave, coalesced
        acc.x = fmaf(xs, w.x, acc.x);
        acc.y = fmaf(xs, w.y, acc.y);
        acc.z = fmaf(xs, w.z, acc.z);
        acc.w = fmaf(xs, w.w, acc.w);
    }

    ((float4*)part)[(size_t)kc * COL4 + col4] = acc;
}

// Stage 2: out[j] = b[j] + sum_kc part[kc][j]
__global__ __launch_bounds__(THREADS)
void reduce_bias_kernel(const float* __restrict__ part,
                        const float* __restrict__ b,
                        float* __restrict__ out) {
    const int col4 = blockIdx.x * THREADS + threadIdx.x;    // one float4 col
    const float4* __restrict__ p4 = (const float4*)part + col4;

    float4 acc = ((const float4*)b)[col4];
#pragma unroll 16
    for (int kc = 0; kc < N_KCHUNK; ++kc) {
        const float4 v = p4[(size_t)kc * COL4];
        acc.x += v.x;
        acc.y += v.y;
        acc.z += v.z;
        acc.w += v.w;
    }
    ((float4*)out)[col4] = acc;
}

extern "C" void kernel_launch(void* const* d_in, const int* in_sizes, int n_in,
                              void* d_out, int out_size, void* d_ws, size_t ws_size,
                              hipStream_t stream) {
    const float* x = (const float*)d_in[0];   // (1, 8192)
    const float* W = (const float*)d_in[1];   // (8192, 8192) row-major
    const float* b = (const float*)d_in[2];   // (8192,)
    float* out  = (float*)d_out;              // (1, 8192)
    float* part = (float*)d_ws;               // 256 * 8192 * 4 B = 8 MB

    dim3 grid1(N_CBLK, N_KCHUNK);             // (8, 256) = 2048 blocks
    matvec_partial_kernel<<<grid1, dim3(THREADS), 0, stream>>>(x, W, part);

    dim3 grid2(N_CBLK);                       // 8 blocks
    reduce_bias_kernel<<<grid2, dim3(THREADS), 0, stream>>>(part, b, out);
}